// Round 1
// baseline (218.755 us; speedup 1.0000x reference)
//
#include <hip/hip_runtime.h>
#include <hip/hip_bf16.h>
#include <stdint.h>

// MoEDecoder: B=64,T=256,IN=256,HID=512,OUT=256,L=2,E=16,S=1
// N_tok = 16384. route_id per batch => 256 consecutive tokens share expert.
// Plan: bf16-convert operands; pre-sum Wc[l,e] = Ws[l,0]+Wr[l,e] (and biases);
// then 4 MFMA GEMMs: proj -> layer0 -> layer1 -> out.

typedef __attribute__((ext_vector_type(8))) short bf16x8;
typedef __attribute__((ext_vector_type(4))) float f32x4;

static __device__ __forceinline__ uint16_t f2bf(float f) {
  union { float f; uint32_t u; } c; c.f = f;
  uint32_t r = (c.u + 0x7FFFu + ((c.u >> 16) & 1u)) >> 16;
  return (uint16_t)r;
}
static __device__ __forceinline__ float bf2f(uint16_t h) {
  union { uint32_t u; float f; } c; c.u = ((uint32_t)h) << 16;
  return c.f;
}

__global__ __launch_bounds__(256) void k_f32_to_bf16(
    const float* __restrict__ in, uint16_t* __restrict__ out, int n4) {
  int i = blockIdx.x * 256 + threadIdx.x;
  if (i < n4) {
    float4 v = ((const float4*)in)[i];
    ushort4 o;
    o.x = f2bf(v.x); o.y = f2bf(v.y); o.z = f2bf(v.z); o.w = f2bf(v.w);
    ((ushort4*)out)[i] = o;
  }
}

// Wc[l,e,:,:] = Ws[l,0,:,:] + Wr[l,e,:,:]  (bf16 out). Flat over Wr elements.
__global__ __launch_bounds__(256) void k_combine_w(
    const float* __restrict__ Ws, const float* __restrict__ Wr,
    uint16_t* __restrict__ Wc, int n4) {
  int i = blockIdx.x * 256 + threadIdx.x;
  if (i >= n4) return;
  int idx = i * 4;
  int l = idx >> 22;                 // / (16*512*512)
  int within = idx & (262144 - 1);   // % (512*512)
  float4 a = *(const float4*)(Ws + l * 262144 + within);
  float4 b = *(const float4*)(Wr + idx);
  ushort4 o;
  o.x = f2bf(a.x + b.x); o.y = f2bf(a.y + b.y);
  o.z = f2bf(a.z + b.z); o.w = f2bf(a.w + b.w);
  ((ushort4*)Wc)[i] = o;
}

// bc[l,e,n] = bs[l,0,n] + br[l,e,n]  (f32)
__global__ __launch_bounds__(256) void k_combine_b(
    const float* __restrict__ bs, const float* __restrict__ br,
    float* __restrict__ bc, int n) {
  int i = blockIdx.x * 256 + threadIdx.x;
  if (i < n) {
    int l = i >> 13;      // / (16*512)
    int j = i & 511;      // % 512
    bc[i] = bs[l * 512 + j] + br[i];
  }
}

// C[M,N] = A[M,K] * B[N,K]^T (+bias)(+resid)(relu). bf16 in, f32 accum.
// Block: 64x64 tile, 4 waves in 2x2, each wave 32x32 via 2x2 mfma 16x16x32.
// MODE 0: bf16 out, relu, no resid (input proj)
// MODE 1: bf16 out, relu, +resid, expert-select B/bias via route (layer)
// MODE 2: f32 out, no relu (output proj)
template <int MODE>
__global__ __launch_bounds__(256) void k_gemm(
    const uint16_t* __restrict__ A, const uint16_t* __restrict__ Bw,
    const float* __restrict__ bias, const uint16_t* __restrict__ resid,
    void* __restrict__ Cout, int M, int N, int K,
    const int* __restrict__ route, int lidx) {
  int wave = threadIdx.x >> 6;
  int lane = threadIdx.x & 63;
  int bm = blockIdx.x, bn = blockIdx.y;

  if (MODE == 1) {
    int e = route[(bm * 64) >> 8];       // batch = row/256
    int off = lidx * 16 + e;
    Bw += (size_t)off * 512 * 512;
    bias += off * 512;
  }

  int row0 = bm * 64 + (wave >> 1) * 32;
  int col0 = bn * 64 + (wave & 1) * 32;
  int lr = lane & 15;          // row (A) / col (B,D) within 16
  int lk = (lane >> 4) * 8;    // k-offset within 32

  const uint16_t* a0p = A + (size_t)(row0 + lr) * K + lk;
  const uint16_t* a1p = a0p + (size_t)16 * K;
  const uint16_t* b0p = Bw + (size_t)(col0 + lr) * K + lk;
  const uint16_t* b1p = b0p + (size_t)16 * K;

  f32x4 acc[2][2] = {{{0.f,0.f,0.f,0.f},{0.f,0.f,0.f,0.f}},
                     {{0.f,0.f,0.f,0.f},{0.f,0.f,0.f,0.f}}};

  for (int k = 0; k < K; k += 32) {
    bf16x8 a0 = *(const bf16x8*)(a0p + k);
    bf16x8 a1 = *(const bf16x8*)(a1p + k);
    bf16x8 b0 = *(const bf16x8*)(b0p + k);
    bf16x8 b1 = *(const bf16x8*)(b1p + k);
    acc[0][0] = __builtin_amdgcn_mfma_f32_16x16x32_bf16(a0, b0, acc[0][0], 0, 0, 0);
    acc[0][1] = __builtin_amdgcn_mfma_f32_16x16x32_bf16(a0, b1, acc[0][1], 0, 0, 0);
    acc[1][0] = __builtin_amdgcn_mfma_f32_16x16x32_bf16(a1, b0, acc[1][0], 0, 0, 0);
    acc[1][1] = __builtin_amdgcn_mfma_f32_16x16x32_bf16(a1, b1, acc[1][1], 0, 0, 0);
  }

  int rbase = (lane >> 4) * 4;
  #pragma unroll
  for (int i = 0; i < 2; i++) {
    #pragma unroll
    for (int j = 0; j < 2; j++) {
      int col = col0 + j * 16 + lr;
      float bv = bias[col];
      #pragma unroll
      for (int r = 0; r < 4; r++) {
        int row = row0 + i * 16 + rbase + r;
        float v = acc[i][j][r] + bv;
        if (MODE == 1) v += bf2f(resid[(size_t)row * N + col]);
        if (MODE != 2) v = fmaxf(v, 0.0f);
        if (MODE == 2) ((float*)Cout)[(size_t)row * N + col] = v;
        else ((uint16_t*)Cout)[(size_t)row * N + col] = f2bf(v);
      }
    }
  }
}

extern "C" void kernel_launch(void* const* d_in, const int* in_sizes, int n_in,
                              void* d_out, int out_size, void* d_ws, size_t ws_size,
                              hipStream_t stream) {
  const float* x     = (const float*)d_in[0];
  const int*   route = (const int*)d_in[1];
  const float* Wi    = (const float*)d_in[2];
  const float* bi    = (const float*)d_in[3];
  const float* Wr    = (const float*)d_in[4];
  const float* br    = (const float*)d_in[5];
  const float* Ws    = (const float*)d_in[6];
  const float* bs    = (const float*)d_in[7];
  const float* Wo    = (const float*)d_in[8];
  const float* bo    = (const float*)d_in[9];

  char* ws = (char*)d_ws;
  uint16_t* Xb  = (uint16_t*)(ws);                  //  8,388,608 B  x bf16
  uint16_t* Wib = (uint16_t*)(ws + 8388608);        //    262,144   Wi bf16
  uint16_t* Wcb = (uint16_t*)(ws + 8650752);        // 16,777,216   Ws+Wr bf16
  uint16_t* Wob = (uint16_t*)(ws + 25427968);       //    262,144   Wo bf16
  float*    bc  = (float*)   (ws + 25690112);       //     65,536   bs+br f32
  uint16_t* hA  = (uint16_t*)(ws + 25755648);       // 16,777,216   h ping
  uint16_t* hB  = (uint16_t*)(ws + 42532864);       // 16,777,216   h pong
  // total 59,310,080 bytes

  // ---- convert / pre-combine ----
  k_f32_to_bf16<<<4096, 256, 0, stream>>>(x, Xb, 1048576);     // 16384*256/4
  k_f32_to_bf16<<<128, 256, 0, stream>>>(Wi, Wib, 32768);      // 512*256/4
  k_f32_to_bf16<<<128, 256, 0, stream>>>(Wo, Wob, 32768);      // 256*512/4
  k_combine_w<<<8192, 256, 0, stream>>>(Ws, Wr, Wcb, 2097152); // 2*16*512*512/4
  k_combine_b<<<64, 256, 0, stream>>>(bs, br, bc, 16384);      // 2*16*512

  // ---- GEMM chain ----
  dim3 blk(256);
  dim3 g1(16384 / 64, 512 / 64);
  // h0 = relu(X * Wi^T + bi)          M=16384 N=512 K=256
  k_gemm<0><<<g1, blk, 0, stream>>>(Xb, Wib, bi, nullptr, hA,
                                    16384, 512, 256, nullptr, 0);
  // layer 0: hB = relu(hA*Wc[0,e]^T + bc[0,e] + hA)   K=512
  k_gemm<1><<<g1, blk, 0, stream>>>(hA, Wcb, bc, hA, hB,
                                    16384, 512, 512, route, 0);
  // layer 1: hA = relu(hB*Wc[1,e]^T + bc[1,e] + hB)
  k_gemm<1><<<g1, blk, 0, stream>>>(hB, Wcb, bc, hB, hA,
                                    16384, 512, 512, route, 1);
  // out = hA * Wo^T + bo              M=16384 N=256 K=512, f32 out
  dim3 g2(16384 / 64, 256 / 64);
  k_gemm<2><<<g2, blk, 0, stream>>>(hA, Wob, bo, nullptr, d_out,
                                    16384, 256, 512, nullptr, 0);
}

// Round 2
// 97.022 us; speedup vs baseline: 2.2547x; 2.2547x over previous
//
#include <hip/hip_runtime.h>
#include <hip/hip_bf16.h>
#include <stdint.h>

// MoEDecoder: B=64,T=256,IN=256,HID=512,OUT=256,L=2,E=16,S=1
// N_tok = 16384. route_id per batch => 256 consecutive tokens share expert;
// 128-row tiles => uniform expert per block (batch = bm>>1).
// bf16-convert operands; pre-sum Wc[l,e] = Ws[l,0]+Wr[l,e] (biases too);
// 4 MFMA GEMMs (m97 structure: 128x128 tile, global_load_lds w16, BK=32).

typedef __attribute__((ext_vector_type(8))) short bf16x8;
typedef __attribute__((ext_vector_type(4))) float f32x4;

static __device__ __forceinline__ uint16_t f2bf(float f) {
  union { float f; uint32_t u; } c; c.f = f;
  uint32_t r = (c.u + 0x7FFFu + ((c.u >> 16) & 1u)) >> 16;
  return (uint16_t)r;
}
static __device__ __forceinline__ float bf2f(uint16_t h) {
  union { uint32_t u; float f; } c; c.u = ((uint32_t)h) << 16;
  return c.f;
}

// async 16B global -> LDS (wave-uniform base + lane*16 pattern)
static __device__ __forceinline__ void glds16(const uint16_t* g, uint16_t* l) {
  __builtin_amdgcn_global_load_lds(
      (const __attribute__((address_space(1))) uint32_t*)g,
      (__attribute__((address_space(3))) uint32_t*)l, 16, 0, 0);
}

__global__ __launch_bounds__(256) void k_f32_to_bf16(
    const float* __restrict__ in, uint16_t* __restrict__ out, int n4) {
  int i = blockIdx.x * 256 + threadIdx.x;
  if (i < n4) {
    float4 v = ((const float4*)in)[i];
    ushort4 o;
    o.x = f2bf(v.x); o.y = f2bf(v.y); o.z = f2bf(v.z); o.w = f2bf(v.w);
    ((ushort4*)out)[i] = o;
  }
}

// Wc[l,e,:,:] = Ws[l,0,:,:] + Wr[l,e,:,:]  (bf16 out). Flat over Wr elements.
__global__ __launch_bounds__(256) void k_combine_w(
    const float* __restrict__ Ws, const float* __restrict__ Wr,
    uint16_t* __restrict__ Wc, int n4) {
  int i = blockIdx.x * 256 + threadIdx.x;
  if (i >= n4) return;
  int idx = i * 4;
  int l = idx >> 22;                 // / (16*512*512)
  int within = idx & (262144 - 1);   // % (512*512)
  float4 a = *(const float4*)(Ws + l * 262144 + within);
  float4 b = *(const float4*)(Wr + idx);
  ushort4 o;
  o.x = f2bf(a.x + b.x); o.y = f2bf(a.y + b.y);
  o.z = f2bf(a.z + b.z); o.w = f2bf(a.w + b.w);
  ((ushort4*)Wc)[i] = o;
}

// bc[l,e,n] = bs[l,0,n] + br[l,e,n]  (f32)
__global__ __launch_bounds__(256) void k_combine_b(
    const float* __restrict__ bs, const float* __restrict__ br,
    float* __restrict__ bc, int n) {
  int i = blockIdx.x * 256 + threadIdx.x;
  if (i < n) {
    int l = i >> 13;      // / (16*512)
    int j = i & 511;      // % 512
    bc[i] = bs[l * 512 + j] + br[i];
  }
}

// C[M,N] = A[M,K] * B[N,K]^T (+bias)(+resid)(relu). bf16 in, f32 accum.
// m97 structure: 128x128 tile, 4 waves (2x2), each wave 64x64 = 4x4 frags of
// 16x16x32 MFMA. BK=32. LDS staged via global_load_lds width=16 (linear
// [128][32] layout — required by wave-uniform-base+lane*16 semantics).
// MODE 0: bf16 out, relu           (input proj)
// MODE 1: bf16 out, relu, +resid, expert-select B/bias via route (layer)
// MODE 2: f32 out, no relu         (output proj)
template <int MODE>
__global__ __launch_bounds__(256) void k_gemm(
    const uint16_t* __restrict__ A, const uint16_t* __restrict__ Bw,
    const float* __restrict__ bias, const uint16_t* __restrict__ resid,
    void* __restrict__ Cout, int M, int N, int K,
    const int* __restrict__ route, int lidx) {
  __shared__ uint16_t lA[128 * 32];
  __shared__ uint16_t lB[128 * 32];

  int tid = threadIdx.x;
  int wave = tid >> 6, lane = tid & 63;
  int bm = blockIdx.x, bn = blockIdx.y;
  int wr = wave >> 1, wc = wave & 1;

  if (MODE == 1) {
    int e = route[bm >> 1];            // 128 rows per block, 256 per batch
    size_t off = (size_t)(lidx * 16 + e);
    Bw += off * 512 * 512;
    bias += off * 512;
  }

  const int row0 = bm * 128, col0 = bn * 128;

  // staging source addresses: thread t covers row t/4 (+64), cols (t%4)*8..+8
  int srow = tid >> 2;
  int scol = (tid & 3) * 8;
  const uint16_t* gA0 = A + (size_t)(row0 + srow) * K + scol;
  const uint16_t* gA1 = gA0 + (size_t)64 * K;
  const uint16_t* gB0 = Bw + (size_t)(col0 + srow) * K + scol;
  const uint16_t* gB1 = gB0 + (size_t)64 * K;
  uint16_t* sA0 = lA + tid * 8;
  uint16_t* sA1 = lA + 2048 + tid * 8;
  uint16_t* sB0 = lB + tid * 8;
  uint16_t* sB1 = lB + 2048 + tid * 8;

  // fragment read bases: lane lr=row-in-16, lk=(lane>>4)*8 k-offset
  int lr = lane & 15;
  int lk = (lane >> 4) * 8;
  const uint16_t* pA = lA + (size_t)(wr * 64 + lr) * 32 + lk;
  const uint16_t* pB = lB + (size_t)(wc * 64 + lr) * 32 + lk;

  f32x4 acc[4][4];
  #pragma unroll
  for (int m = 0; m < 4; m++)
    #pragma unroll
    for (int n = 0; n < 4; n++)
      acc[m][n] = (f32x4){0.f, 0.f, 0.f, 0.f};

  for (int k0 = 0; k0 < K; k0 += 32) {
    glds16(gA0 + k0, sA0);
    glds16(gA1 + k0, sA1);
    glds16(gB0 + k0, sB0);
    glds16(gB1 + k0, sB1);
    __syncthreads();              // drains vmcnt -> LDS tiles ready

    bf16x8 a[4], b[4];
    #pragma unroll
    for (int m = 0; m < 4; m++) a[m] = *(const bf16x8*)(pA + m * 16 * 32);
    #pragma unroll
    for (int n = 0; n < 4; n++) b[n] = *(const bf16x8*)(pB + n * 16 * 32);
    #pragma unroll
    for (int m = 0; m < 4; m++)
      #pragma unroll
      for (int n = 0; n < 4; n++)
        acc[m][n] = __builtin_amdgcn_mfma_f32_16x16x32_bf16(a[m], b[n],
                                                            acc[m][n], 0, 0, 0);
    __syncthreads();              // protect LDS before next stage
  }

  // epilogue: D row=(lane>>4)*4+reg, col=lane&15 (per-frag), verified R1
  int rb = (lane >> 4) * 4;
  #pragma unroll
  for (int n = 0; n < 4; n++) {
    int col = col0 + wc * 64 + n * 16 + lr;
    float bv = bias[col];
    #pragma unroll
    for (int m = 0; m < 4; m++) {
      #pragma unroll
      for (int r = 0; r < 4; r++) {
        int row = row0 + wr * 64 + m * 16 + rb + r;
        float v = acc[m][n][r] + bv;
        if (MODE == 1) v += bf2f(resid[(size_t)row * N + col]);
        if (MODE != 2) v = fmaxf(v, 0.0f);
        if (MODE == 2) ((float*)Cout)[(size_t)row * N + col] = v;
        else ((uint16_t*)Cout)[(size_t)row * N + col] = f2bf(v);
      }
    }
  }
}

extern "C" void kernel_launch(void* const* d_in, const int* in_sizes, int n_in,
                              void* d_out, int out_size, void* d_ws, size_t ws_size,
                              hipStream_t stream) {
  const float* x     = (const float*)d_in[0];
  const int*   route = (const int*)d_in[1];
  const float* Wi    = (const float*)d_in[2];
  const float* bi    = (const float*)d_in[3];
  const float* Wr    = (const float*)d_in[4];
  const float* br    = (const float*)d_in[5];
  const float* Ws    = (const float*)d_in[6];
  const float* bs    = (const float*)d_in[7];
  const float* Wo    = (const float*)d_in[8];
  const float* bo    = (const float*)d_in[9];

  char* ws = (char*)d_ws;
  uint16_t* Xb  = (uint16_t*)(ws);                  //  8,388,608 B  x bf16
  uint16_t* Wib = (uint16_t*)(ws + 8388608);        //    262,144   Wi bf16
  uint16_t* Wcb = (uint16_t*)(ws + 8650752);        // 16,777,216   Ws+Wr bf16
  uint16_t* Wob = (uint16_t*)(ws + 25427968);       //    262,144   Wo bf16
  float*    bc  = (float*)   (ws + 25690112);       //     65,536   bs+br f32
  uint16_t* hA  = (uint16_t*)(ws + 25755648);       // 16,777,216   h ping
  uint16_t* hB  = (uint16_t*)(ws + 42532864);       // 16,777,216   h pong
  // total 59,310,080 bytes

  // ---- convert / pre-combine ----
  k_f32_to_bf16<<<4096, 256, 0, stream>>>(x, Xb, 1048576);     // 16384*256/4
  k_f32_to_bf16<<<128, 256, 0, stream>>>(Wi, Wib, 32768);      // 512*256/4
  k_f32_to_bf16<<<128, 256, 0, stream>>>(Wo, Wob, 32768);      // 256*512/4
  k_combine_w<<<8192, 256, 0, stream>>>(Ws, Wr, Wcb, 2097152); // 2*16*512*512/4
  k_combine_b<<<64, 256, 0, stream>>>(bs, br, bc, 16384);      // 2*16*512

  // ---- GEMM chain (128x128 tiles) ----
  dim3 blk(256);
  dim3 g1(16384 / 128, 512 / 128);
  // h0 = relu(X * Wi^T + bi)          M=16384 N=512 K=256
  k_gemm<0><<<g1, blk, 0, stream>>>(Xb, Wib, bi, nullptr, hA,
                                    16384, 512, 256, nullptr, 0);
  // layer 0: hB = relu(hA*Wc[0,e]^T + bc[0,e] + hA)   K=512
  k_gemm<1><<<g1, blk, 0, stream>>>(hA, Wcb, bc, hA, hB,
                                    16384, 512, 512, route, 0);
  // layer 1: hA = relu(hB*Wc[1,e]^T + bc[1,e] + hB)
  k_gemm<1><<<g1, blk, 0, stream>>>(hB, Wcb, bc, hB, hA,
                                    16384, 512, 512, route, 1);
  // out = hA * Wo^T + bo              M=16384 N=256 K=512, f32 out
  dim3 g2(16384 / 128, 256 / 128);
  k_gemm<2><<<g2, blk, 0, stream>>>(hA, Wob, bo, nullptr, d_out,
                                    16384, 256, 512, nullptr, 0);
}